// Round 9
// baseline (892.764 us; speedup 1.0000x reference)
//
#include <hip/hip_runtime.h>

#define HID    128
#define SEQ    512
#define BATCH  256
#define DIM    300
#define VOCAB  50000
#define WT_FLOATS 40960  // 160 KB slot for packed-transposed W_ih (needs 38400)

typedef float f32x2 __attribute__((ext_vector_type(2)));

// packed fp32 FMA: d.x=a.x*b.x+c.x ; d.y=a.y*b.y+c.y  (VOP3P, CDNA)
__device__ __forceinline__ f32x2 pk_fma(f32x2 a, f32x2 b, f32x2 c)
{
    f32x2 d;
    asm("v_pk_fma_f32 %0, %1, %2, %3" : "=v"(d) : "v"(a), "v"(b), "v"(c));
    return d;
}

// ---------------------------------------------------------------------------
// Kernel 0 (R4-proven): pack-transpose W_ih [128][300] -> Wt[k4][h][4].
// ---------------------------------------------------------------------------
__global__ __launch_bounds__(256)
void wtrans_kernel(const float* __restrict__ Wih, float* __restrict__ Wt)
{
    int idx = blockIdx.x * 256 + threadIdx.x;
    if (idx < HID * DIM) {
        int h = idx / DIM;
        int k = idx - h * DIM;
        Wt[(k >> 2) * (HID * 4) + h * 4 + (k & 3)] = Wih[idx];
    }
}

// ---------------------------------------------------------------------------
// Kernel A (R8-proven, byte-identical): coalesced staging + R4 inner loop.
// ---------------------------------------------------------------------------
#define ETP 20
#define VT  16
__global__ __launch_bounds__(128)
void proj_fast(const float* __restrict__ emb,
               const float* __restrict__ Wt,
               const float* __restrict__ bih,
               const float* __restrict__ bhh,
               float* __restrict__ P)
{
    __shared__ float et[DIM][ETP];   // transposed emb tile: et[k][r]
    const int t  = threadIdx.x;
    const int hp = t & 63;
    const int rg8 = (t >> 6) * 8;
    const int v0 = blockIdx.x * VT;

    // coalesced staging: rr = local row, kk = float4 phase
    {
        const int rr = t >> 3;          // 0..15
        const int kk = t & 7;           // 0..7
        const float* src = emb + (size_t)(v0 + rr) * DIM;
        #pragma unroll
        for (int p = 0; p < 10; ++p) {
            const int f4 = kk + 8 * p;  // 0..74
            if (f4 < DIM / 4) {
                const float4 ev = *(const float4*)(src + f4 * 4);
                et[4 * f4 + 0][rr] = ev.x;
                et[4 * f4 + 1][rr] = ev.y;
                et[4 * f4 + 2][rr] = ev.z;
                et[4 * f4 + 3][rr] = ev.w;
            }
        }
    }
    __syncthreads();

    float a00=0.f,a10=0.f,a20=0.f,a30=0.f,a40=0.f,a50=0.f,a60=0.f,a70=0.f;
    float a01=0.f,a11=0.f,a21=0.f,a31=0.f,a41=0.f,a51=0.f,a61=0.f,a71=0.f;

    const float* wp0 = Wt + hp * 4;          // packed: [k4][h][4]
    const float* wp1 = Wt + (hp + 64) * 4;

    for (int k4 = 0; k4 < DIM / 4; ++k4) {
        const float4 wa4 = *(const float4*)(wp0 + k4 * (HID * 4));
        const float4 wb4 = *(const float4*)(wp1 + k4 * (HID * 4));
        #pragma unroll
        for (int jj = 0; jj < 4; ++jj) {
            const float wa = (jj==0)?wa4.x:(jj==1)?wa4.y:(jj==2)?wa4.z:wa4.w;
            const float wb = (jj==0)?wb4.x:(jj==1)?wb4.y:(jj==2)?wb4.z:wb4.w;
            const int k = k4 * 4 + jj;
            const float4 e0 = *(const float4*)(&et[k][rg8]);      // broadcast
            const float4 e1 = *(const float4*)(&et[k][rg8 + 4]);  // broadcast
            a00 = fmaf(wa, e0.x, a00);  a01 = fmaf(wb, e0.x, a01);
            a10 = fmaf(wa, e0.y, a10);  a11 = fmaf(wb, e0.y, a11);
            a20 = fmaf(wa, e0.z, a20);  a21 = fmaf(wb, e0.z, a21);
            a30 = fmaf(wa, e0.w, a30);  a31 = fmaf(wb, e0.w, a31);
            a40 = fmaf(wa, e1.x, a40);  a41 = fmaf(wb, e1.x, a41);
            a50 = fmaf(wa, e1.y, a50);  a51 = fmaf(wb, e1.y, a51);
            a60 = fmaf(wa, e1.z, a60);  a61 = fmaf(wb, e1.z, a61);
            a70 = fmaf(wa, e1.w, a70);  a71 = fmaf(wb, e1.w, a71);
        }
    }

    const float bb0 = bih[hp] + bhh[hp];
    const float bb1 = bih[hp + 64] + bhh[hp + 64];
    float* dst = P + (size_t)(v0 + rg8) * HID;
    dst[0*HID + hp] = a00 + bb0;  dst[0*HID + hp + 64] = a01 + bb1;
    dst[1*HID + hp] = a10 + bb0;  dst[1*HID + hp + 64] = a11 + bb1;
    dst[2*HID + hp] = a20 + bb0;  dst[2*HID + hp + 64] = a21 + bb1;
    dst[3*HID + hp] = a30 + bb0;  dst[3*HID + hp + 64] = a31 + bb1;
    dst[4*HID + hp] = a40 + bb0;  dst[4*HID + hp + 64] = a41 + bb1;
    dst[5*HID + hp] = a50 + bb0;  dst[5*HID + hp + 64] = a51 + bb1;
    dst[6*HID + hp] = a60 + bb0;  dst[6*HID + hp + 64] = a61 + bb1;
    dst[7*HID + hp] = a70 + bb0;  dst[7*HID + hp + 64] = a71 + bb1;
}

// ---------------------------------------------------------------------------
// Kernel A (fallback, R3-proven): used only if ws_size can't fit Wt + P.
// ---------------------------------------------------------------------------
__global__ __launch_bounds__(128)
void proj_fallback(const float* __restrict__ emb,
                   const float* __restrict__ Wih,
                   const float* __restrict__ bih,
                   const float* __restrict__ bhh,
                   float* __restrict__ P)
{
    __shared__ float et[DIM][ETP];
    const int t  = threadIdx.x;
    const int hp = t & 63;
    const int rg8 = (t >> 6) * 8;
    const int v0 = blockIdx.x * VT;

    #pragma unroll
    for (int r = 0; r < VT; ++r) {
        const float* src = emb + (size_t)(v0 + r) * DIM;
        for (int k = t; k < DIM; k += 128)
            et[k][r] = src[k];
    }
    __syncthreads();

    float a00=0.f,a10=0.f,a20=0.f,a30=0.f,a40=0.f,a50=0.f,a60=0.f,a70=0.f;
    float a01=0.f,a11=0.f,a21=0.f,a31=0.f,a41=0.f,a51=0.f,a61=0.f,a71=0.f;

    const float* w0 = Wih + (size_t)hp * DIM;
    const float* w1 = Wih + (size_t)(hp + 64) * DIM;

    for (int k4 = 0; k4 < DIM / 4; ++k4) {
        const float4 wa4 = *(const float4*)(w0 + k4 * 4);
        const float4 wb4 = *(const float4*)(w1 + k4 * 4);
        #pragma unroll
        for (int jj = 0; jj < 4; ++jj) {
            const float wa = (jj==0)?wa4.x:(jj==1)?wa4.y:(jj==2)?wa4.z:wa4.w;
            const float wb = (jj==0)?wb4.x:(jj==1)?wb4.y:(jj==2)?wb4.z:wb4.w;
            const int k = k4 * 4 + jj;
            const float4 e0 = *(const float4*)(&et[k][rg8]);
            const float4 e1 = *(const float4*)(&et[k][rg8 + 4]);
            a00 = fmaf(wa, e0.x, a00);  a01 = fmaf(wb, e0.x, a01);
            a10 = fmaf(wa, e0.y, a10);  a11 = fmaf(wb, e0.y, a11);
            a20 = fmaf(wa, e0.z, a20);  a21 = fmaf(wb, e0.z, a21);
            a30 = fmaf(wa, e0.w, a30);  a31 = fmaf(wb, e0.w, a31);
            a40 = fmaf(wa, e1.x, a40);  a41 = fmaf(wb, e1.x, a41);
            a50 = fmaf(wa, e1.y, a50);  a51 = fmaf(wb, e1.y, a51);
            a60 = fmaf(wa, e1.z, a60);  a61 = fmaf(wb, e1.z, a61);
            a70 = fmaf(wa, e1.w, a70);  a71 = fmaf(wb, e1.w, a71);
        }
    }

    const float bb0 = bih[hp] + bhh[hp];
    const float bb1 = bih[hp + 64] + bhh[hp + 64];
    float* dst = P + (size_t)(v0 + rg8) * HID;
    dst[0*HID + hp] = a00 + bb0;  dst[0*HID + hp + 64] = a01 + bb1;
    dst[1*HID + hp] = a10 + bb0;  dst[1*HID + hp + 64] = a11 + bb1;
    dst[2*HID + hp] = a20 + bb0;  dst[2*HID + hp + 64] = a21 + bb1;
    dst[3*HID + hp] = a30 + bb0;  dst[3*HID + hp + 64] = a31 + bb1;
    dst[4*HID + hp] = a40 + bb0;  dst[4*HID + hp + 64] = a41 + bb1;
    dst[5*HID + hp] = a50 + bb0;  dst[5*HID + hp + 64] = a51 + bb1;
    dst[6*HID + hp] = a60 + bb0;  dst[6*HID + hp + 64] = a61 + bb1;
    dst[7*HID + hp] = a70 + bb0;  dst[7*HID + hp + 64] = a71 + bb1;
}

// ---------------------------------------------------------------------------
// Kernel B: ONE WAVE per batch element — zero barriers.
// Lane l owns rows 2l, 2l+1; W_hh rows in 256 VGPRs (f32x2, static-indexed).
// Per step: 32 broadcast ds_read_b128 (full h, same-wave in-order LDS pipe,
// no barrier needed) + 128 v_pk_fma_f32 + 2 fast-tanh + 1 ds_write_b64.
// wave_barrier() = zero-cost compiler fence pinning write->read order.
// P gathers coalesced (512B/row across 64 lanes), 4 steps deep, never
// drained (no syncthreads => no vmcnt(0)).
// ---------------------------------------------------------------------------
__global__ __launch_bounds__(64, 1)
void rnn_wave(const int* __restrict__ x,
              const float* __restrict__ Whh,
              const float* __restrict__ P,
              const float* __restrict__ fcw,
              const float* __restrict__ fcb,
              float* __restrict__ out)
{
    __shared__ float hA[HID];
    __shared__ float hB[HID];
    __shared__ int   toff[SEQ];     // token*HID, premultiplied

    const int l  = threadIdx.x;     // 0..63
    const int b  = blockIdx.x;
    const int r0 = 2 * l;           // rows 2l, 2l+1

    #pragma unroll
    for (int q = 0; q < 8; ++q)
        toff[q * 64 + l] = x[b * SEQ + q * 64 + l] * HID;

    // W_hh rows 2l, 2l+1 into registers as f32x2[64] each (256 VGPRs)
    f32x2 w0[64], w1[64];
    {
        const float* p0 = Whh + (size_t)r0 * HID;
        #pragma unroll
        for (int q = 0; q < 32; ++q) {
            const float4 v = *(const float4*)(p0 + q * 4);
            w0[2*q]   = f32x2{v.x, v.y};
            w0[2*q+1] = f32x2{v.z, v.w};
        }
        const float* p1 = Whh + (size_t)(r0 + 1) * HID;
        #pragma unroll
        for (int q = 0; q < 32; ++q) {
            const float4 v = *(const float4*)(p1 + q * 4);
            w1[2*q]   = f32x2{v.x, v.y};
            w1[2*q+1] = f32x2{v.z, v.w};
        }
    }

    *(f32x2*)(hA + r0) = f32x2{0.f, 0.f};   // h = 0
    __builtin_amdgcn_wave_barrier();

    float hmax0 = -3.0e38f, hsum0 = 0.f;
    float hmax1 = -3.0e38f, hsum1 = 0.f;

    // x prefetch, 4 deep
    f32x2 x0 = *(const f32x2*)(P + toff[0] + r0);
    f32x2 x1 = *(const f32x2*)(P + toff[1] + r0);
    f32x2 x2 = *(const f32x2*)(P + toff[2] + r0);
    f32x2 x3 = *(const f32x2*)(P + toff[3] + r0);

#define STEP(HRD, HWR, XT) do {                                               \
        f32x2 a00={0.f,0.f}, a01={0.f,0.f}, a02={0.f,0.f}, a03={0.f,0.f};     \
        f32x2 a10={0.f,0.f}, a11={0.f,0.f}, a12={0.f,0.f}, a13={0.f,0.f};     \
        const f32x2* hv = (const f32x2*)(HRD);                                \
        _Pragma("unroll")                                                     \
        for (int q = 0; q < 64; q += 4) {                                     \
            const f32x2 h0_ = hv[q+0], h1_ = hv[q+1];                         \
            const f32x2 h2_ = hv[q+2], h3_ = hv[q+3];                         \
            a00 = pk_fma(w0[q+0], h0_, a00); a10 = pk_fma(w1[q+0], h0_, a10); \
            a01 = pk_fma(w0[q+1], h1_, a01); a11 = pk_fma(w1[q+1], h1_, a11); \
            a02 = pk_fma(w0[q+2], h2_, a02); a12 = pk_fma(w1[q+2], h2_, a12); \
            a03 = pk_fma(w0[q+3], h3_, a03); a13 = pk_fma(w1[q+3], h3_, a13); \
        }                                                                     \
        const f32x2 s0 = (a00 + a01) + (a02 + a03);                           \
        const f32x2 s1 = (a10 + a11) + (a12 + a13);                           \
        const float z0 = (XT).x + s0.x + s0.y;                                \
        const float z1 = (XT).y + s1.x + s1.y;                                \
        const float e0 = __builtin_amdgcn_exp2f(z0 * 2.8853900817779268f);    \
        const float h0n = fmaf(-2.f, __builtin_amdgcn_rcpf(e0 + 1.f), 1.f);   \
        const float e1 = __builtin_amdgcn_exp2f(z1 * 2.8853900817779268f);    \
        const float h1n = fmaf(-2.f, __builtin_amdgcn_rcpf(e1 + 1.f), 1.f);   \
        hmax0 = fmaxf(hmax0, h0n); hsum0 += h0n;                              \
        hmax1 = fmaxf(hmax1, h1n); hsum1 += h1n;                              \
        *(f32x2*)((HWR) + r0) = f32x2{h0n, h1n};                              \
        __builtin_amdgcn_wave_barrier();                                      \
    } while (0)

    for (int s4 = 0; s4 < SEQ / 4 - 1; ++s4) {
        const int sb = s4 * 4 + 4;
        const f32x2 n0 = *(const f32x2*)(P + toff[sb + 0] + r0);
        const f32x2 n1 = *(const f32x2*)(P + toff[sb + 1] + r0);
        const f32x2 n2 = *(const f32x2*)(P + toff[sb + 2] + r0);
        const f32x2 n3 = *(const f32x2*)(P + toff[sb + 3] + r0);
        STEP(hA, hB, x0);
        STEP(hB, hA, x1);
        STEP(hA, hB, x2);
        STEP(hB, hA, x3);
        x0 = n0; x1 = n1; x2 = n2; x3 = n3;
    }
    STEP(hA, hB, x0);
    STEP(hB, hA, x1);
    STEP(hA, hB, x2);
    STEP(hB, hA, x3);
#undef STEP

    // fused pooling + FC (per-lane rows 2l, 2l+1), then wave reduce
    const f32x2 fwm = *(const f32x2*)(fcw + r0);
    const f32x2 fwa = *(const f32x2*)(fcw + HID + r0);
    float red = fwm.x * hmax0 + fwm.y * hmax1
              + fwa.x * (hsum0 * (1.f / 512.f))
              + fwa.y * (hsum1 * (1.f / 512.f));
    #pragma unroll
    for (int m = 32; m >= 1; m >>= 1) red += __shfl_xor(red, m);
    if (l == 0) out[b] = red + fcb[0];
}

// ---------------------------------------------------------------------------
extern "C" void kernel_launch(void* const* d_in, const int* in_sizes, int n_in,
                              void* d_out, int out_size, void* d_ws, size_t ws_size,
                              hipStream_t stream)
{
    const int*   x   = (const int*)  d_in[0];
    const float* emb = (const float*)d_in[1];
    const float* Wih = (const float*)d_in[2];
    const float* Whh = (const float*)d_in[3];
    const float* bih = (const float*)d_in[4];
    const float* bhh = (const float*)d_in[5];
    const float* fcw = (const float*)d_in[6];
    const float* fcb = (const float*)d_in[7];

    float* base = (float*)d_ws;
    const size_t need = (WT_FLOATS + (size_t)VOCAB * HID) * sizeof(float);
    float* P;

    if (ws_size >= need) {
        float* Wt = base;                 // 160 KB, inside d_ws (proven R4)
        P = base + WT_FLOATS;
        wtrans_kernel<<<(HID * DIM + 255) / 256, 256, 0, stream>>>(Wih, Wt);
        proj_fast<<<VOCAB / VT, 128, 0, stream>>>(emb, Wt, bih, bhh, P);
    } else {
        P = base;
        proj_fallback<<<VOCAB / VT, 128, 0, stream>>>(emb, Wih, bih, bhh, P);
    }

    rnn_wave<<<BATCH, 64, 0, stream>>>(x, Whh, P, fcw, fcb, (float*)d_out);
}

// Round 10
// 268.147 us; speedup vs baseline: 3.3294x; 3.3294x over previous
//
#include <hip/hip_runtime.h>

#define HID    128
#define SEQ    512
#define BATCH  256
#define DIM    300
#define VOCAB  50000
#define WT_FLOATS 40960  // 160 KB slot for packed-transposed W_ih (needs 38400)

typedef float f32x2 __attribute__((ext_vector_type(2)));

// packed fp32 FMA (VOP3P, 2 MAC/inst) — compiled & ran in R9
__device__ __forceinline__ f32x2 pk_fma(f32x2 a, f32x2 b, f32x2 c)
{
    f32x2 d;
    asm("v_pk_fma_f32 %0, %1, %2, %3" : "=v"(d) : "v"(a), "v"(b), "v"(c));
    return d;
}

// ---------------------------------------------------------------------------
// Kernel 0 (R4-proven): pack-transpose W_ih [128][300] -> Wt[k4][h][4].
// ---------------------------------------------------------------------------
__global__ __launch_bounds__(256)
void wtrans_kernel(const float* __restrict__ Wih, float* __restrict__ Wt)
{
    int idx = blockIdx.x * 256 + threadIdx.x;
    if (idx < HID * DIM) {
        int h = idx / DIM;
        int k = idx - h * DIM;
        Wt[(k >> 2) * (HID * 4) + h * 4 + (k & 3)] = Wih[idx];
    }
}

// ---------------------------------------------------------------------------
// Kernel A: proj, 4h x 8r blocking, 32 rows/block.
// 128 thr = 32 h-groups (t&31: h0=4*hg) x 4 row-groups (t>>5: rg8=8*rg).
// Per k: 2 broadcast ds_read_b128 feed 32 MACs (16 pk_fma) -> half the
// LDS reads of the R8 proj at same reads/wave (waves halve).
// et stride 36 (16B-aligned, rg8 addresses hit distinct bank quads).
// W: 4 coalesced float4/lane/k4 from packed Wt (L2-hot).
// ---------------------------------------------------------------------------
#define PR4   32            // rows per block
#define PST   36            // et stride: 16B-aligned, +4 pad
__global__ __launch_bounds__(128)
void proj_fast4(const float* __restrict__ emb,
                const float* __restrict__ Wt,
                const float* __restrict__ bih,
                const float* __restrict__ bhh,
                float* __restrict__ P)
{
    __shared__ float et[DIM * PST];   // et[k][r] transposed; 43.2 KB
    const int t   = threadIdx.x;
    const int hg  = t & 31;
    const int h0  = hg * 4;
    const int rg8 = (t >> 5) * 8;
    const int v0  = blockIdx.x * PR4;

    // coalesced staging: rr = local row (t>>2), kk = float4 phase (t&3)
    {
        const int rr = t >> 2;          // 0..31
        const int kk = t & 3;           // 0..3
        int row = v0 + rr; if (row > VOCAB - 1) row = VOCAB - 1;
        const float* src = emb + (size_t)row * DIM;
        #pragma unroll
        for (int p = 0; p < 19; ++p) {
            const int f4 = kk + 4 * p;  // 0..75
            if (f4 < DIM / 4) {
                const float4 ev = *(const float4*)(src + f4 * 4);
                et[(4*f4+0) * PST + rr] = ev.x;
                et[(4*f4+1) * PST + rr] = ev.y;
                et[(4*f4+2) * PST + rr] = ev.z;
                et[(4*f4+3) * PST + rr] = ev.w;
            }
        }
    }
    __syncthreads();

    f32x2 acc[4][4];   // [h][row-pair]
    #pragma unroll
    for (int j = 0; j < 4; ++j)
        #pragma unroll
        for (int rp = 0; rp < 4; ++rp) acc[j][rp] = f32x2{0.f, 0.f};

    const float* wb = Wt + h0 * 4;
    for (int k4 = 0; k4 < DIM / 4; ++k4) {
        const float4 wA = *(const float4*)(wb + k4 * (HID*4) + 0);
        const float4 wB = *(const float4*)(wb + k4 * (HID*4) + 4);
        const float4 wC = *(const float4*)(wb + k4 * (HID*4) + 8);
        const float4 wD = *(const float4*)(wb + k4 * (HID*4) + 12);
        #pragma unroll
        for (int jj = 0; jj < 4; ++jj) {
            const int k = k4 * 4 + jj;
            const float4 e0 = *(const float4*)(&et[k * PST + rg8]);      // bcast
            const float4 e1 = *(const float4*)(&et[k * PST + rg8 + 4]);  // bcast
            const f32x2 p0 = {e0.x, e0.y}, p1 = {e0.z, e0.w};
            const f32x2 p2 = {e1.x, e1.y}, p3 = {e1.z, e1.w};
            const float va = (jj==0)?wA.x:(jj==1)?wA.y:(jj==2)?wA.z:wA.w;
            const float vb = (jj==0)?wB.x:(jj==1)?wB.y:(jj==2)?wB.z:wB.w;
            const float vc = (jj==0)?wC.x:(jj==1)?wC.y:(jj==2)?wC.z:wC.w;
            const float vd = (jj==0)?wD.x:(jj==1)?wD.y:(jj==2)?wD.z:wD.w;
            const f32x2 wa2 = {va, va}, wb2 = {vb, vb};
            const f32x2 wc2 = {vc, vc}, wd2 = {vd, vd};
            acc[0][0] = pk_fma(p0, wa2, acc[0][0]);
            acc[0][1] = pk_fma(p1, wa2, acc[0][1]);
            acc[0][2] = pk_fma(p2, wa2, acc[0][2]);
            acc[0][3] = pk_fma(p3, wa2, acc[0][3]);
            acc[1][0] = pk_fma(p0, wb2, acc[1][0]);
            acc[1][1] = pk_fma(p1, wb2, acc[1][1]);
            acc[1][2] = pk_fma(p2, wb2, acc[1][2]);
            acc[1][3] = pk_fma(p3, wb2, acc[1][3]);
            acc[2][0] = pk_fma(p0, wc2, acc[2][0]);
            acc[2][1] = pk_fma(p1, wc2, acc[2][1]);
            acc[2][2] = pk_fma(p2, wc2, acc[2][2]);
            acc[2][3] = pk_fma(p3, wc2, acc[2][3]);
            acc[3][0] = pk_fma(p0, wd2, acc[3][0]);
            acc[3][1] = pk_fma(p1, wd2, acc[3][1]);
            acc[3][2] = pk_fma(p2, wd2, acc[3][2]);
            acc[3][3] = pk_fma(p3, wd2, acc[3][3]);
        }
    }

    float bb[4];
    #pragma unroll
    for (int j = 0; j < 4; ++j) bb[j] = bih[h0+j] + bhh[h0+j];

    // write 8 rows x 4 h (float4 per row, coalesced across hg lanes)
    #pragma unroll
    for (int c = 0; c < 8; ++c) {
        const int row = v0 + rg8 + c;
        if (row < VOCAB) {
            const int rp = c >> 1, hi = c & 1;
            float4 o;
            o.x = (hi ? acc[0][rp].y : acc[0][rp].x) + bb[0];
            o.y = (hi ? acc[1][rp].y : acc[1][rp].x) + bb[1];
            o.z = (hi ? acc[2][rp].y : acc[2][rp].x) + bb[2];
            o.w = (hi ? acc[3][rp].y : acc[3][rp].x) + bb[3];
            *(float4*)(P + (size_t)row * HID + h0) = o;
        }
    }
}

// ---------------------------------------------------------------------------
// Kernel A (fallback, R3-proven): used only if ws_size can't fit Wt + P.
// ---------------------------------------------------------------------------
#define ETP 20
#define VT  16
__global__ __launch_bounds__(128)
void proj_fallback(const float* __restrict__ emb,
                   const float* __restrict__ Wih,
                   const float* __restrict__ bih,
                   const float* __restrict__ bhh,
                   float* __restrict__ P)
{
    __shared__ float et[DIM][ETP];
    const int t  = threadIdx.x;
    const int hp = t & 63;
    const int rg8 = (t >> 6) * 8;
    const int v0 = blockIdx.x * VT;

    #pragma unroll
    for (int r = 0; r < VT; ++r) {
        const float* src = emb + (size_t)(v0 + r) * DIM;
        for (int k = t; k < DIM; k += 128)
            et[k][r] = src[k];
    }
    __syncthreads();

    float a00=0.f,a10=0.f,a20=0.f,a30=0.f,a40=0.f,a50=0.f,a60=0.f,a70=0.f;
    float a01=0.f,a11=0.f,a21=0.f,a31=0.f,a41=0.f,a51=0.f,a61=0.f,a71=0.f;

    const float* w0 = Wih + (size_t)hp * DIM;
    const float* w1 = Wih + (size_t)(hp + 64) * DIM;

    for (int k4 = 0; k4 < DIM / 4; ++k4) {
        const float4 wa4 = *(const float4*)(w0 + k4 * 4);
        const float4 wb4 = *(const float4*)(w1 + k4 * 4);
        #pragma unroll
        for (int jj = 0; jj < 4; ++jj) {
            const float wa = (jj==0)?wa4.x:(jj==1)?wa4.y:(jj==2)?wa4.z:wa4.w;
            const float wb = (jj==0)?wb4.x:(jj==1)?wb4.y:(jj==2)?wb4.z:wb4.w;
            const int k = k4 * 4 + jj;
            const float4 e0 = *(const float4*)(&et[k][rg8]);
            const float4 e1 = *(const float4*)(&et[k][rg8 + 4]);
            a00 = fmaf(wa, e0.x, a00);  a01 = fmaf(wb, e0.x, a01);
            a10 = fmaf(wa, e0.y, a10);  a11 = fmaf(wb, e0.y, a11);
            a20 = fmaf(wa, e0.z, a20);  a21 = fmaf(wb, e0.z, a21);
            a30 = fmaf(wa, e0.w, a30);  a31 = fmaf(wb, e0.w, a31);
            a40 = fmaf(wa, e1.x, a40);  a41 = fmaf(wb, e1.x, a41);
            a50 = fmaf(wa, e1.y, a50);  a51 = fmaf(wb, e1.y, a51);
            a60 = fmaf(wa, e1.z, a60);  a61 = fmaf(wb, e1.z, a61);
            a70 = fmaf(wa, e1.w, a70);  a71 = fmaf(wb, e1.w, a71);
        }
    }

    const float bb0 = bih[hp] + bhh[hp];
    const float bb1 = bih[hp + 64] + bhh[hp + 64];
    float* dst = P + (size_t)(v0 + rg8) * HID;
    dst[0*HID + hp] = a00 + bb0;  dst[0*HID + hp + 64] = a01 + bb1;
    dst[1*HID + hp] = a10 + bb0;  dst[1*HID + hp + 64] = a11 + bb1;
    dst[2*HID + hp] = a20 + bb0;  dst[2*HID + hp + 64] = a21 + bb1;
    dst[3*HID + hp] = a30 + bb0;  dst[3*HID + hp + 64] = a31 + bb1;
    dst[4*HID + hp] = a40 + bb0;  dst[4*HID + hp + 64] = a41 + bb1;
    dst[5*HID + hp] = a50 + bb0;  dst[5*HID + hp + 64] = a51 + bb1;
    dst[6*HID + hp] = a60 + bb0;  dst[6*HID + hp + 64] = a61 + bb1;
    dst[7*HID + hp] = a70 + bb0;  dst[7*HID + hp + 64] = a71 + bb1;
}

// ---------------------------------------------------------------------------
// Kernel B: RNN — BYTE-IDENTICAL to R8 (164-166 µs measured).
// ---------------------------------------------------------------------------
__device__ __forceinline__ float quad_sum(float v)
{
    int x1 = __builtin_amdgcn_update_dpp(0, __float_as_int(v), 0xB1, 0xF, 0xF, true);
    v += __int_as_float(x1);
    int x2 = __builtin_amdgcn_update_dpp(0, __float_as_int(v), 0x4E, 0xF, 0xF, true);
    v += __int_as_float(x2);
    return v;
}

__global__ __launch_bounds__(512)
void rnn_kernel(const int* __restrict__ x,
                const float* __restrict__ Whh,
                const float* __restrict__ P,
                const float* __restrict__ fcw,
                const float* __restrict__ fcb,
                float* __restrict__ out)
{
    __shared__ float h0b[HID];
    __shared__ float h1b[HID];
    __shared__ int   toff[SEQ];
    __shared__ float xb[2 * 64 * HID];
    __shared__ float red[HID];

    const int t  = threadIdx.x;
    const int b  = blockIdx.x;
    const int i  = t >> 2;
    const int kq = t & 3;

    toff[t] = x[b * SEQ + t] * HID;
    if (t < HID) h0b[t] = 0.f;

    float4 w[8];
    #pragma unroll
    for (int j = 0; j < 8; ++j) {
        const int pj = (j + 2 * kq) & 7;
        w[j] = *(const float4*)(Whh + (size_t)i * HID + kq * 32 + pj * 4);
    }
    __syncthreads();

#define STAGE(cn) do {                                                        \
        const int w_ = t >> 6, l_ = t & 63;                                   \
        const int base_ = ((cn) & 1) * (64 * HID);                            \
        _Pragma("unroll")                                                     \
        for (int q_ = 0; q_ < 4; ++q_) {                                      \
            const int row_ = w_ * 8 + q_ * 2 + (l_ >> 5);                     \
            const int col_ = (l_ & 31) * 4;                                   \
            const int off_ = toff[(cn) * 64 + row_] + col_;                   \
            const float4 v_ = *(const float4*)(P + off_);                     \
            *(float4*)(&xb[base_ + row_ * HID + col_]) = v_;                  \
        }                                                                     \
    } while (0)

    STAGE(0);
    __syncthreads();

    float hmax = -3.0e38f, hsum = 0.f;

#define STEP(HRD, HWR, XPTR, SOFF) do {                                       \
        const float xt = (XPTR)[(SOFF) * HID];                                \
        float ac0=0.f,ac1=0.f,ac2=0.f,ac3=0.f,ac4=0.f,ac5=0.f,ac6=0.f,ac7=0.f;\
        _Pragma("unroll")                                                     \
        for (int j = 0; j < 8; ++j) {                                         \
            const int pj = (j + 2 * kq) & 7;                                  \
            const float4 h4 = *(const float4*)((HRD) + kq * 32 + pj * 4);     \
            float* ap = (j==0)?&ac0:(j==1)?&ac1:(j==2)?&ac2:(j==3)?&ac3       \
                       :(j==4)?&ac4:(j==5)?&ac5:(j==6)?&ac6:&ac7;             \
            *ap = fmaf(w[j].x, h4.x, *ap);                                    \
            *ap = fmaf(w[j].y, h4.y, *ap);                                    \
            *ap = fmaf(w[j].z, h4.z, *ap);                                    \
            *ap = fmaf(w[j].w, h4.w, *ap);                                    \
        }                                                                     \
        float acc = ((ac0+ac1)+(ac2+ac3)) + ((ac4+ac5)+(ac6+ac7));            \
        acc = quad_sum(acc);                                                  \
        const float z = xt + acc;                                             \
        const float e = __builtin_amdgcn_exp2f(z * 2.8853900817779268f);      \
        const float hnew = fmaf(-2.f, __builtin_amdgcn_rcpf(e + 1.f), 1.f);   \
        hmax = fmaxf(hmax, hnew);                                             \
        hsum += hnew;                                                         \
        (HWR)[i] = hnew;                                                      \
        __syncthreads();                                                      \
    } while (0)

    for (int c = 0; c < 8; ++c) {
        if (c < 7) STAGE(c + 1);
        const float* xp = &xb[(c & 1) * (64 * HID) + i];
        #pragma unroll 4
        for (int u = 0; u < 32; ++u) {
            STEP(h0b, h1b, xp, u * 2);
            STEP(h1b, h0b, xp, u * 2 + 1);
        }
    }
#undef STEP
#undef STAGE

    if (kq == 0)
        red[i] = fcw[i] * hmax + fcw[HID + i] * (hsum * (1.f / 512.f));
    __syncthreads();
    if (t < 64) {
        float v = red[t] + red[t + 64];
        #pragma unroll
        for (int m = 32; m >= 1; m >>= 1) v += __shfl_xor(v, m);
        if (t == 0) out[b] = v + fcb[0];
    }
}

// ---------------------------------------------------------------------------
extern "C" void kernel_launch(void* const* d_in, const int* in_sizes, int n_in,
                              void* d_out, int out_size, void* d_ws, size_t ws_size,
                              hipStream_t stream)
{
    const int*   x   = (const int*)  d_in[0];
    const float* emb = (const float*)d_in[1];
    const float* Wih = (const float*)d_in[2];
    const float* Whh = (const float*)d_in[3];
    const float* bih = (const float*)d_in[4];
    const float* bhh = (const float*)d_in[5];
    const float* fcw = (const float*)d_in[6];
    const float* fcb = (const float*)d_in[7];

    float* base = (float*)d_ws;
    const size_t need = (WT_FLOATS + (size_t)VOCAB * HID) * sizeof(float);
    float* P;

    if (ws_size >= need) {
        float* Wt = base;                 // 160 KB, inside d_ws (proven R4)
        P = base + WT_FLOATS;
        wtrans_kernel<<<(HID * DIM + 255) / 256, 256, 0, stream>>>(Wih, Wt);
        proj_fast4<<<(VOCAB + PR4 - 1) / PR4, 128, 0, stream>>>(emb, Wt, bih, bhh, P);
    } else {
        P = base;
        proj_fallback<<<VOCAB / VT, 128, 0, stream>>>(emb, Wih, bih, bhh, P);
    }

    rnn_kernel<<<BATCH, 512, 0, stream>>>(x, Whh, P, fcw, fcb, (float*)d_out);
}

// Round 11
// 227.104 us; speedup vs baseline: 3.9311x; 1.1807x over previous
//
#include <hip/hip_runtime.h>

#define HID    128
#define SEQ    512
#define BATCH  256
#define DIM    300
#define VOCAB  50000
#define WT_FLOATS 40960  // 160 KB slot for packed-transposed W_ih (needs 38400)

// ---------------------------------------------------------------------------
// Kernel 0 (R4-proven): pack-transpose W_ih [128][300] -> Wt[k4][h][4].
// ---------------------------------------------------------------------------
__global__ __launch_bounds__(256)
void wtrans_kernel(const float* __restrict__ Wih, float* __restrict__ Wt)
{
    int idx = blockIdx.x * 256 + threadIdx.x;
    if (idx < HID * DIM) {
        int h = idx / DIM;
        int k = idx - h * DIM;
        Wt[(k >> 2) * (HID * 4) + h * 4 + (k & 3)] = Wih[idx];
    }
}

// ---------------------------------------------------------------------------
// Kernel A: proj at 6 waves/SIMD. 256 thr, 16 rows/block, 24 KB LDS
// (6 blocks x 4 waves = 24 waves/CU — double R8's 3/SIMD hiding).
// Per-thread: 2h x 4r (half of R8's work, SAME inner-loop shape).
// e-read: one ds_read_b128 per k, single-address per wave (t>>6 is
// wave-uniform) -> pure broadcast, conflict-free.
// Occupancy experiment: latency-bound => ~45 µs; LDS-throughput => ~70.
// ---------------------------------------------------------------------------
#define ETP 20
#define VT  16
__global__ __launch_bounds__(256)
void proj_fast256(const float* __restrict__ emb,
                  const float* __restrict__ Wt,
                  const float* __restrict__ bih,
                  const float* __restrict__ bhh,
                  float* __restrict__ P)
{
    __shared__ float et[DIM][ETP];   // transposed emb tile: et[k][r], 24 KB
    const int t   = threadIdx.x;     // 0..255
    const int hp  = t & 63;
    const int rg4 = ((t >> 6) & 3) * 4;   // wave-uniform row group {0,4,8,12}
    const int v0  = blockIdx.x * VT;

    // coalesced staging: rr = local row (t>>4), kk = float4 phase (t&15)
    {
        const int rr = t >> 4;          // 0..15
        const int kk = t & 15;          // 0..15
        const float* src = emb + (size_t)(v0 + rr) * DIM;
        #pragma unroll
        for (int p = 0; p < 5; ++p) {
            const int f4 = kk + 16 * p; // 0..79
            if (f4 < DIM / 4) {
                const float4 ev = *(const float4*)(src + f4 * 4);
                et[4 * f4 + 0][rr] = ev.x;
                et[4 * f4 + 1][rr] = ev.y;
                et[4 * f4 + 2][rr] = ev.z;
                et[4 * f4 + 3][rr] = ev.w;
            }
        }
    }
    __syncthreads();

    float a00=0.f,a10=0.f,a20=0.f,a30=0.f;   // h=hp,    rows rg4..rg4+3
    float a01=0.f,a11=0.f,a21=0.f,a31=0.f;   // h=hp+64, rows rg4..rg4+3

    const float* wp0 = Wt + hp * 4;          // packed: [k4][h][4]
    const float* wp1 = Wt + (hp + 64) * 4;

    for (int k4 = 0; k4 < DIM / 4; ++k4) {
        const float4 wa4 = *(const float4*)(wp0 + k4 * (HID * 4));
        const float4 wb4 = *(const float4*)(wp1 + k4 * (HID * 4));
        #pragma unroll
        for (int jj = 0; jj < 4; ++jj) {
            const float wa = (jj==0)?wa4.x:(jj==1)?wa4.y:(jj==2)?wa4.z:wa4.w;
            const float wb = (jj==0)?wb4.x:(jj==1)?wb4.y:(jj==2)?wb4.z:wb4.w;
            const int k = k4 * 4 + jj;
            const float4 e0 = *(const float4*)(&et[k][rg4]);   // wave-bcast
            a00 = fmaf(wa, e0.x, a00);  a01 = fmaf(wb, e0.x, a01);
            a10 = fmaf(wa, e0.y, a10);  a11 = fmaf(wb, e0.y, a11);
            a20 = fmaf(wa, e0.z, a20);  a21 = fmaf(wb, e0.z, a21);
            a30 = fmaf(wa, e0.w, a30);  a31 = fmaf(wb, e0.w, a31);
        }
    }

    const float bb0 = bih[hp] + bhh[hp];
    const float bb1 = bih[hp + 64] + bhh[hp + 64];
    float* dst = P + (size_t)(v0 + rg4) * HID;
    dst[0*HID + hp] = a00 + bb0;  dst[0*HID + hp + 64] = a01 + bb1;
    dst[1*HID + hp] = a10 + bb0;  dst[1*HID + hp + 64] = a11 + bb1;
    dst[2*HID + hp] = a20 + bb0;  dst[2*HID + hp + 64] = a21 + bb1;
    dst[3*HID + hp] = a30 + bb0;  dst[3*HID + hp + 64] = a31 + bb1;
}

// ---------------------------------------------------------------------------
// Kernel A (fallback, R3-proven): used only if ws_size can't fit Wt + P.
// ---------------------------------------------------------------------------
__global__ __launch_bounds__(128)
void proj_fallback(const float* __restrict__ emb,
                   const float* __restrict__ Wih,
                   const float* __restrict__ bih,
                   const float* __restrict__ bhh,
                   float* __restrict__ P)
{
    __shared__ float et[DIM][ETP];
    const int t  = threadIdx.x;
    const int hp = t & 63;
    const int rg8 = (t >> 6) * 8;
    const int v0 = blockIdx.x * VT;

    #pragma unroll
    for (int r = 0; r < VT; ++r) {
        const float* src = emb + (size_t)(v0 + r) * DIM;
        for (int k = t; k < DIM; k += 128)
            et[k][r] = src[k];
    }
    __syncthreads();

    float a00=0.f,a10=0.f,a20=0.f,a30=0.f,a40=0.f,a50=0.f,a60=0.f,a70=0.f;
    float a01=0.f,a11=0.f,a21=0.f,a31=0.f,a41=0.f,a51=0.f,a61=0.f,a71=0.f;

    const float* w0 = Wih + (size_t)hp * DIM;
    const float* w1 = Wih + (size_t)(hp + 64) * DIM;

    for (int k4 = 0; k4 < DIM / 4; ++k4) {
        const float4 wa4 = *(const float4*)(w0 + k4 * 4);
        const float4 wb4 = *(const float4*)(w1 + k4 * 4);
        #pragma unroll
        for (int jj = 0; jj < 4; ++jj) {
            const float wa = (jj==0)?wa4.x:(jj==1)?wa4.y:(jj==2)?wa4.z:wa4.w;
            const float wb = (jj==0)?wb4.x:(jj==1)?wb4.y:(jj==2)?wb4.z:wb4.w;
            const int k = k4 * 4 + jj;
            const float4 e0 = *(const float4*)(&et[k][rg8]);
            const float4 e1 = *(const float4*)(&et[k][rg8 + 4]);
            a00 = fmaf(wa, e0.x, a00);  a01 = fmaf(wb, e0.x, a01);
            a10 = fmaf(wa, e0.y, a10);  a11 = fmaf(wb, e0.y, a11);
            a20 = fmaf(wa, e0.z, a20);  a21 = fmaf(wb, e0.z, a21);
            a30 = fmaf(wa, e0.w, a30);  a31 = fmaf(wb, e0.w, a31);
            a40 = fmaf(wa, e1.x, a40);  a41 = fmaf(wb, e1.x, a41);
            a50 = fmaf(wa, e1.y, a50);  a51 = fmaf(wb, e1.y, a51);
            a60 = fmaf(wa, e1.z, a60);  a61 = fmaf(wb, e1.z, a61);
            a70 = fmaf(wa, e1.w, a70);  a71 = fmaf(wb, e1.w, a71);
        }
    }

    const float bb0 = bih[hp] + bhh[hp];
    const float bb1 = bih[hp + 64] + bhh[hp + 64];
    float* dst = P + (size_t)(v0 + rg8) * HID;
    dst[0*HID + hp] = a00 + bb0;  dst[0*HID + hp + 64] = a01 + bb1;
    dst[1*HID + hp] = a10 + bb0;  dst[1*HID + hp + 64] = a11 + bb1;
    dst[2*HID + hp] = a20 + bb0;  dst[2*HID + hp + 64] = a21 + bb1;
    dst[3*HID + hp] = a30 + bb0;  dst[3*HID + hp + 64] = a31 + bb1;
    dst[4*HID + hp] = a40 + bb0;  dst[4*HID + hp + 64] = a41 + bb1;
    dst[5*HID + hp] = a50 + bb0;  dst[5*HID + hp + 64] = a51 + bb1;
    dst[6*HID + hp] = a60 + bb0;  dst[6*HID + hp + 64] = a61 + bb1;
    dst[7*HID + hp] = a70 + bb0;  dst[7*HID + hp + 64] = a71 + bb1;
}

// ---------------------------------------------------------------------------
// Kernel B: RNN — BYTE-IDENTICAL to R8 (164-166 µs measured).
// ---------------------------------------------------------------------------
__device__ __forceinline__ float quad_sum(float v)
{
    int x1 = __builtin_amdgcn_update_dpp(0, __float_as_int(v), 0xB1, 0xF, 0xF, true);
    v += __int_as_float(x1);
    int x2 = __builtin_amdgcn_update_dpp(0, __float_as_int(v), 0x4E, 0xF, 0xF, true);
    v += __int_as_float(x2);
    return v;
}

__global__ __launch_bounds__(512)
void rnn_kernel(const int* __restrict__ x,
                const float* __restrict__ Whh,
                const float* __restrict__ P,
                const float* __restrict__ fcw,
                const float* __restrict__ fcb,
                float* __restrict__ out)
{
    __shared__ float h0b[HID];
    __shared__ float h1b[HID];
    __shared__ int   toff[SEQ];
    __shared__ float xb[2 * 64 * HID];
    __shared__ float red[HID];

    const int t  = threadIdx.x;
    const int b  = blockIdx.x;
    const int i  = t >> 2;
    const int kq = t & 3;

    toff[t] = x[b * SEQ + t] * HID;
    if (t < HID) h0b[t] = 0.f;

    float4 w[8];
    #pragma unroll
    for (int j = 0; j < 8; ++j) {
        const int pj = (j + 2 * kq) & 7;
        w[j] = *(const float4*)(Whh + (size_t)i * HID + kq * 32 + pj * 4);
    }
    __syncthreads();

#define STAGE(cn) do {                                                        \
        const int w_ = t >> 6, l_ = t & 63;                                   \
        const int base_ = ((cn) & 1) * (64 * HID);                            \
        _Pragma("unroll")                                                     \
        for (int q_ = 0; q_ < 4; ++q_) {                                      \
            const int row_ = w_ * 8 + q_ * 2 + (l_ >> 5);                     \
            const int col_ = (l_ & 31) * 4;                                   \
            const int off_ = toff[(cn) * 64 + row_] + col_;                   \
            const float4 v_ = *(const float4*)(P + off_);                     \
            *(float4*)(&xb[base_ + row_ * HID + col_]) = v_;                  \
        }                                                                     \
    } while (0)

    STAGE(0);
    __syncthreads();

    float hmax = -3.0e38f, hsum = 0.f;

#define STEP(HRD, HWR, XPTR, SOFF) do {                                       \
        const float xt = (XPTR)[(SOFF) * HID];                                \
        float ac0=0.f,ac1=0.f,ac2=0.f,ac3=0.f,ac4=0.f,ac5=0.f,ac6=0.f,ac7=0.f;\
        _Pragma("unroll")                                                     \
        for (int j = 0; j < 8; ++j) {                                         \
            const int pj = (j + 2 * kq) & 7;                                  \
            const float4 h4 = *(const float4*)((HRD) + kq * 32 + pj * 4);     \
            float* ap = (j==0)?&ac0:(j==1)?&ac1:(j==2)?&ac2:(j==3)?&ac3       \
                       :(j==4)?&ac4:(j==5)?&ac5:(j==6)?&ac6:&ac7;             \
            *ap = fmaf(w[j].x, h4.x, *ap);                                    \
            *ap = fmaf(w[j].y, h4.y, *ap);                                    \
            *ap = fmaf(w[j].z, h4.z, *ap);                                    \
            *ap = fmaf(w[j].w, h4.w, *ap);                                    \
        }                                                                     \
        float acc = ((ac0+ac1)+(ac2+ac3)) + ((ac4+ac5)+(ac6+ac7));            \
        acc = quad_sum(acc);                                                  \
        const float z = xt + acc;                                             \
        const float e = __builtin_amdgcn_exp2f(z * 2.8853900817779268f);      \
        const float hnew = fmaf(-2.f, __builtin_amdgcn_rcpf(e + 1.f), 1.f);   \
        hmax = fmaxf(hmax, hnew);                                             \
        hsum += hnew;                                                         \
        (HWR)[i] = hnew;                                                      \
        __syncthreads();                                                      \
    } while (0)

    for (int c = 0; c < 8; ++c) {
        if (c < 7) STAGE(c + 1);
        const float* xp = &xb[(c & 1) * (64 * HID) + i];
        #pragma unroll 4
        for (int u = 0; u < 32; ++u) {
            STEP(h0b, h1b, xp, u * 2);
            STEP(h1b, h0b, xp, u * 2 + 1);
        }
    }
#undef STEP
#undef STAGE

    if (kq == 0)
        red[i] = fcw[i] * hmax + fcw[HID + i] * (hsum * (1.f / 512.f));
    __syncthreads();
    if (t < 64) {
        float v = red[t] + red[t + 64];
        #pragma unroll
        for (int m = 32; m >= 1; m >>= 1) v += __shfl_xor(v, m);
        if (t == 0) out[b] = v + fcb[0];
    }
}

// ---------------------------------------------------------------------------
extern "C" void kernel_launch(void* const* d_in, const int* in_sizes, int n_in,
                              void* d_out, int out_size, void* d_ws, size_t ws_size,
                              hipStream_t stream)
{
    const int*   x   = (const int*)  d_in[0];
    const float* emb = (const float*)d_in[1];
    const float* Wih = (const float*)d_in[2];
    const float* Whh = (const float*)d_in[3];
    const float* bih = (const float*)d_in[4];
    const float* bhh = (const float*)d_in[5];
    const float* fcw = (const float*)d_in[6];
    const float* fcb = (const float*)d_in[7];

    float* base = (float*)d_ws;
    const size_t need = (WT_FLOATS + (size_t)VOCAB * HID) * sizeof(float);
    float* P;

    if (ws_size >= need) {
        float* Wt = base;                 // 160 KB, inside d_ws (proven R4)
        P = base + WT_FLOATS;
        wtrans_kernel<<<(HID * DIM + 255) / 256, 256, 0, stream>>>(Wih, Wt);
        proj_fast256<<<VOCAB / VT, 256, 0, stream>>>(emb, Wt, bih, bhh, P);
    } else {
        P = base;
        proj_fallback<<<VOCAB / VT, 128, 0, stream>>>(emb, Wih, bih, bhh, P);
    }

    rnn_kernel<<<BATCH, 512, 0, stream>>>(x, Whh, P, fcw, fcb, (float*)d_out);
}